// Round 1
// baseline (290.382 us; speedup 1.0000x reference)
//
#include <hip/hip_runtime.h>

typedef _Float16 half8 __attribute__((ext_vector_type(8)));
typedef _Float16 half4_t __attribute__((ext_vector_type(4)));
typedef short short8 __attribute__((ext_vector_type(8)));
typedef unsigned short u16x4 __attribute__((ext_vector_type(4)));
typedef float f32x4 __attribute__((ext_vector_type(4)));

#define NH 8

__device__ __forceinline__ unsigned short f2bf(float x) {
  union { float f; unsigned u; } v; v.f = x;
  unsigned r = v.u + 0x7FFFu + ((v.u >> 16) & 1u);
  return (unsigned short)(r >> 16);
}

// ---------------- K0: weight prep ----------------
// bigq/bigk: [h][128][512] fp16 hi/lo.  cols 0..63 = W^T, 64..127 = (W @ omega^T)^T
// wvt: [h][64][512] fp16
__global__ __launch_bounds__(256) void k0_prep(
    const float* __restrict__ wq, const float* __restrict__ wv,
    const float* __restrict__ wk, const float* __restrict__ omega,
    _Float16* __restrict__ bigq_h, _Float16* __restrict__ bigq_l,
    _Float16* __restrict__ bigk_h, _Float16* __restrict__ bigk_l,
    _Float16* __restrict__ wvt) {
  int idx = blockIdx.x * 256 + threadIdx.x;
  const int NQ = 2 * NH * 128 * 512;  // 1048576
  if (idx < NQ) {
    int arr = idx >> 19;
    int r = idx & ((1 << 19) - 1);
    int h = r >> 16;
    int o = (r >> 9) & 127;
    int f = r & 511;
    const float* w = arr ? wk : wq;
    float val;
    if (o < 64) {
      val = w[(h * 512 + f) * 64 + o];
    } else {
      const float* wrow = w + (h * 512 + f) * 64;
      const float* om = omega + (o - 64) * 64;
      float s = 0.f;
#pragma unroll 8
      for (int k = 0; k < 64; ++k) s = fmaf(wrow[k], om[k], s);
      val = s;
    }
    _Float16 hi = (_Float16)val;
    _Float16 lo = (_Float16)(val - (float)hi);
    int off = (h * 128 + o) * 512 + f;
    if (arr == 0) { bigq_h[off] = hi; bigq_l[off] = lo; }
    else          { bigk_h[off] = hi; bigk_l[off] = lo; }
  } else {
    int r = idx - NQ;
    if (r < NH * 64 * 512) {
      int h = r >> 15;
      int o = (r >> 9) & 63;
      int f = r & 511;
      wvt[(h * 64 + o) * 512 + f] = (_Float16)wv[(h * 512 + f) * 64 + o];
    }
  }
}

// ---------------- K1/K2a: fused projection + xw GEMM + phi ----------------
// QSIDE=1: x=query -> qp2 fp16 blocked [bh][t/4][128][4]  (needs lsc)
// QSIDE=0: x=key   -> kpt bf16 [bh][128][4096]
template <int QSIDE>
__global__ __launch_bounds__(512, 1) void k_proj_phi(
    const float* __restrict__ x,
    const _Float16* __restrict__ bw_h,
    const _Float16* __restrict__ bw_l,
    const float* __restrict__ lsc,
    _Float16* __restrict__ qp,
    unsigned short* __restrict__ kpt) {
  __shared__ _Float16 Ah[64][72];
  __shared__ _Float16 Al[64][72];
  const int tid = threadIdx.x;
  const int wave = tid >> 6;  // head
  const int lane = tid & 63;
  const int g = lane >> 4;
  const int c = lane & 15;
  const int R0 = blockIdx.x * 64;
  const int b = R0 >> 12;
  const int t0 = R0 & 4095;
  const int bh = b * NH + wave;

  f32x4 acc[4][8];
#pragma unroll
  for (int i = 0; i < 4; ++i)
#pragma unroll
    for (int j = 0; j < 8; ++j) acc[i][j] = (f32x4){0.f, 0.f, 0.f, 0.f};

  const int sr = tid >> 3;
  const int sc = (tid & 7) * 8;
  const _Float16* bhb = bw_h + (size_t)wave * 128 * 512;
  const _Float16* blb = bw_l + (size_t)wave * 128 * 512;

  for (int kc = 0; kc < 8; ++kc) {
    __syncthreads();
    {
      const float* src = x + (size_t)(R0 + sr) * 512 + kc * 64 + sc;
      float4 v0 = *(const float4*)(src);
      float4 v1 = *(const float4*)(src + 4);
      float vv[8] = {v0.x, v0.y, v0.z, v0.w, v1.x, v1.y, v1.z, v1.w};
      half8 hv, lv;
#pragma unroll
      for (int i = 0; i < 8; ++i) {
        _Float16 h = (_Float16)vv[i];
        hv[i] = h;
        lv[i] = (_Float16)(vv[i] - (float)h);
      }
      *(half8*)&Ah[sr][sc] = hv;
      *(half8*)&Al[sr][sc] = lv;
    }
    __syncthreads();
#pragma unroll
    for (int ks = 0; ks < 2; ++ks) {
      half8 a_h[4], a_l[4];
#pragma unroll
      for (int mf = 0; mf < 4; ++mf) {
        a_h[mf] = *(const half8*)&Ah[mf * 16 + c][ks * 32 + g * 8];
        a_l[mf] = *(const half8*)&Al[mf * 16 + c][ks * 32 + g * 8];
      }
      const int koff = kc * 64 + ks * 32 + g * 8;
#pragma unroll
      for (int nf = 0; nf < 4; ++nf) {  // projection cols (only for ss): hi pass only
        half8 b_h = *(const half8*)(bhb + (size_t)(nf * 16 + c) * 512 + koff);
#pragma unroll
        for (int mf = 0; mf < 4; ++mf)
          acc[mf][nf] = __builtin_amdgcn_mfma_f32_16x16x32_f16(a_h[mf], b_h, acc[mf][nf], 0, 0, 0);
      }
#pragma unroll
      for (int nf = 4; nf < 8; ++nf) {  // xw cols: 3-pass split for accuracy
        half8 b_h = *(const half8*)(bhb + (size_t)(nf * 16 + c) * 512 + koff);
        half8 b_l = *(const half8*)(blb + (size_t)(nf * 16 + c) * 512 + koff);
#pragma unroll
        for (int mf = 0; mf < 4; ++mf) {
          acc[mf][nf] = __builtin_amdgcn_mfma_f32_16x16x32_f16(a_h[mf], b_h, acc[mf][nf], 0, 0, 0);
          acc[mf][nf] = __builtin_amdgcn_mfma_f32_16x16x32_f16(a_l[mf], b_h, acc[mf][nf], 0, 0, 0);
          acc[mf][nf] = __builtin_amdgcn_mfma_f32_16x16x32_f16(a_h[mf], b_l, acc[mf][nf], 0, 0, 0);
        }
      }
    }
  }

  float Lp[4], Lm[4];
  if (QSIDE) {
#pragma unroll
    for (int nf = 0; nf < 4; ++nf) {
      Lp[nf] = lsc[bh * 128 + nf * 16 + c];
      Lm[nf] = lsc[bh * 128 + 64 + nf * 16 + c];
    }
  }

#pragma unroll
  for (int mf = 0; mf < 4; ++mf) {
    float ss_[4];
#pragma unroll
    for (int j = 0; j < 4; ++j) {
      float s = 0.f;
#pragma unroll
      for (int nf = 0; nf < 4; ++nf) { float q = acc[mf][nf][j]; s = fmaf(q, q, s); }
      s += __shfl_xor(s, 1); s += __shfl_xor(s, 2);
      s += __shfl_xor(s, 4); s += __shfl_xor(s, 8);
      ss_[j] = 0.5f * s;
    }
    if (QSIDE) {
      float cm_[4];
#pragma unroll
      for (int j = 0; j < 4; ++j) {
        float m0 = -1e30f;
#pragma unroll
        for (int nf = 4; nf < 8; ++nf) {
          float v = acc[mf][nf][j];
          float ep = v - ss_[j] + Lp[nf - 4];
          float em = -v - ss_[j] + Lm[nf - 4];
          m0 = fmaxf(m0, fmaxf(ep, em));
          m0 = fmaxf(m0, fmaxf(Lp[nf - 4], Lm[nf - 4]) - 20.723265f);  // eps floor
        }
        m0 = fmaxf(m0, __shfl_xor(m0, 1)); m0 = fmaxf(m0, __shfl_xor(m0, 2));
        m0 = fmaxf(m0, __shfl_xor(m0, 4)); m0 = fmaxf(m0, __shfl_xor(m0, 8));
        cm_[j] = m0;
      }
      const int t4 = (t0 >> 2) + mf * 4 + g;
#pragma unroll
      for (int nf = 4; nf < 8; ++nf) {
        const int m = (nf - 4) * 16 + c;
        half4_t pp, pm;
#pragma unroll
        for (int j = 0; j < 4; ++j) {
          float v = acc[mf][nf][j];
          pp[j] = (_Float16)(__expf(v - ss_[j] + Lp[nf - 4] - cm_[j]) +
                             1e-9f * __expf(Lp[nf - 4] - cm_[j]));
          pm[j] = (_Float16)(__expf(-v - ss_[j] + Lm[nf - 4] - cm_[j]) +
                             1e-9f * __expf(Lm[nf - 4] - cm_[j]));
        }
        _Float16* outp = qp + ((((size_t)bh * 1024 + t4) * 128 + m) << 2);
        *(half4_t*)outp = pp;
        *(half4_t*)(outp + 256) = pm;  // m+64
      }
    } else {
      const int s_g = t0 + mf * 16 + g * 4;
#pragma unroll
      for (int nf = 4; nf < 8; ++nf) {
        const int m = (nf - 4) * 16 + c;
        u16x4 kp_p, kp_m;
#pragma unroll
        for (int j = 0; j < 4; ++j) {
          float v = acc[mf][nf][j];
          kp_p[j] = f2bf(__expf(v - ss_[j]) + 1e-9f);
          kp_m[j] = f2bf(__expf(-v - ss_[j]) + 1e-9f);
        }
        unsigned short* outp = kpt + ((size_t)bh * 128 + m) * 4096 + s_g;
        *(u16x4*)outp = kp_p;
        *(u16x4*)(outp + (size_t)64 * 4096) = kp_m;
      }
    }
  }
}

// ---------------- K2b: V projection -> VT bf16 [bh][64][4096] ----------------
__global__ __launch_bounds__(512, 1) void k_vproj(
    const float* __restrict__ x, const _Float16* __restrict__ wvt,
    unsigned short* __restrict__ vt) {
  __shared__ _Float16 Ah[64][72];
  const int tid = threadIdx.x;
  const int wave = tid >> 6;
  const int lane = tid & 63;
  const int g = lane >> 4, c = lane & 15;
  const int R0 = blockIdx.x * 64;
  const int b = R0 >> 12;
  const int t0 = R0 & 4095;
  f32x4 acc[4][4];
#pragma unroll
  for (int i = 0; i < 4; ++i)
#pragma unroll
    for (int j = 0; j < 4; ++j) acc[i][j] = (f32x4){0.f, 0.f, 0.f, 0.f};
  const int sr = tid >> 3, sc = (tid & 7) * 8;
  const _Float16* wb = wvt + (size_t)wave * 64 * 512;
  for (int kc = 0; kc < 8; ++kc) {
    __syncthreads();
    {
      const float* src = x + (size_t)(R0 + sr) * 512 + kc * 64 + sc;
      float4 v0 = *(const float4*)(src);
      float4 v1 = *(const float4*)(src + 4);
      float vv[8] = {v0.x, v0.y, v0.z, v0.w, v1.x, v1.y, v1.z, v1.w};
      half8 hv;
#pragma unroll
      for (int i = 0; i < 8; ++i) hv[i] = (_Float16)vv[i];
      *(half8*)&Ah[sr][sc] = hv;
    }
    __syncthreads();
#pragma unroll
    for (int ks = 0; ks < 2; ++ks) {
      half8 a_h[4];
#pragma unroll
      for (int mf = 0; mf < 4; ++mf)
        a_h[mf] = *(const half8*)&Ah[mf * 16 + c][ks * 32 + g * 8];
      const int koff = kc * 64 + ks * 32 + g * 8;
#pragma unroll
      for (int nf = 0; nf < 4; ++nf) {
        half8 b_h = *(const half8*)(wb + (size_t)(nf * 16 + c) * 512 + koff);
#pragma unroll
        for (int mf = 0; mf < 4; ++mf)
          acc[mf][nf] = __builtin_amdgcn_mfma_f32_16x16x32_f16(a_h[mf], b_h, acc[mf][nf], 0, 0, 0);
      }
    }
  }
  const int bh = b * NH + wave;
#pragma unroll
  for (int mf = 0; mf < 4; ++mf) {
    const int s_g = t0 + mf * 16 + g * 4;
#pragma unroll
    for (int nf = 0; nf < 4; ++nf) {
      u16x4 vv;
#pragma unroll
      for (int j = 0; j < 4; ++j) vv[j] = f2bf(acc[mf][nf][j]);
      *(u16x4*)(vt + ((size_t)bh * 64 + nf * 16 + c) * 4096 + s_g) = vv;
    }
  }
}

// ---------------- K3: kv partials [kc][bh][128][80] fp32 ----------------
__global__ __launch_bounds__(256) void k3_kv(
    const unsigned short* __restrict__ kpt, const unsigned short* __restrict__ vt,
    float* __restrict__ kvpart) {
  const int bh = blockIdx.x;
  const int kc = blockIdx.y;
  const int wave = threadIdx.x >> 6;
  const int lane = threadIdx.x & 63;
  const int g = lane >> 4, c = lane & 15;
  f32x4 acc[2][5];
#pragma unroll
  for (int i = 0; i < 2; ++i)
#pragma unroll
    for (int j = 0; j < 5; ++j) acc[i][j] = (f32x4){0.f, 0.f, 0.f, 0.f};
  short8 bones;
#pragma unroll
  for (int i = 0; i < 8; ++i) bones[i] = (c == 0) ? (short)0x3F80 : (short)0;
  const unsigned short* kbase = kpt + (size_t)bh * 128 * 4096;
  const unsigned short* vbase = vt + (size_t)bh * 64 * 4096;
  for (int ks = 0; ks < 16; ++ks) {
    const int soff = kc * 512 + ks * 32 + g * 8;
    short8 a0 = *(const short8*)(kbase + (size_t)(wave * 32 + c) * 4096 + soff);
    short8 a1 = *(const short8*)(kbase + (size_t)(wave * 32 + 16 + c) * 4096 + soff);
#pragma unroll
    for (int nf = 0; nf < 4; ++nf) {
      short8 bb = *(const short8*)(vbase + (size_t)(nf * 16 + c) * 4096 + soff);
      acc[0][nf] = __builtin_amdgcn_mfma_f32_16x16x32_bf16(a0, bb, acc[0][nf], 0, 0, 0);
      acc[1][nf] = __builtin_amdgcn_mfma_f32_16x16x32_bf16(a1, bb, acc[1][nf], 0, 0, 0);
    }
    acc[0][4] = __builtin_amdgcn_mfma_f32_16x16x32_bf16(a0, bones, acc[0][4], 0, 0, 0);
    acc[1][4] = __builtin_amdgcn_mfma_f32_16x16x32_bf16(a1, bones, acc[1][4], 0, 0, 0);
  }
  float* pbase = kvpart + ((size_t)kc * 32 + bh) * 128 * 80;
#pragma unroll
  for (int i = 0; i < 2; ++i)
#pragma unroll
    for (int nf = 0; nf < 5; ++nf)
#pragma unroll
      for (int j = 0; j < 4; ++j) {
        int m = wave * 32 + i * 16 + g * 4 + j;
        pbase[m * 80 + nf * 16 + c] = acc[i][nf][j];
      }
}

// ---------------- K3b: reduce + normalize -> kvnT fp16 [bh][80][128], lsc ----------------
__global__ __launch_bounds__(256) void k3b_reduce(
    const float* __restrict__ kvpart, _Float16* __restrict__ kvnt,
    float* __restrict__ lsc) {
  const int bh = blockIdx.x;
  const int tid = threadIdx.x;
  __shared__ float inv[128];
  const float* base = kvpart + (size_t)bh * 128 * 80;
  const size_t stride = (size_t)32 * 128 * 80;
  if (tid < 128) {
    float s = 0.f;
#pragma unroll
    for (int kc = 0; kc < 8; ++kc) s += base[kc * stride + tid * 80 + 64];
    inv[tid] = 1.0f / s;
    lsc[bh * 128 + tid] = __logf(s);
  }
  __syncthreads();
  for (int it = 0; it < 40; ++it) {
    int idx = it * 256 + tid;
    int d = idx >> 7, m = idx & 127;
    float s = 0.f;
#pragma unroll
    for (int kc = 0; kc < 8; ++kc) s += base[kc * stride + m * 80 + d];
    float val;
    if (d < 64) val = s * inv[m];
    else if (d == 64) val = 1.0f;
    else val = 0.f;
    kvnt[((size_t)bh * 80 + d) * 128 + m] = (_Float16)val;
  }
}

// ---------------- K4: out = (qp2 @ kvn)/(qp2 @ 1) ----------------
__global__ __launch_bounds__(256) void k4_out(
    const _Float16* __restrict__ qp, const _Float16* __restrict__ kvnt,
    float* __restrict__ out) {
  __shared__ unsigned short qlds[64][136];
  const int bh = blockIdx.y;
  const int tt = blockIdx.x;
  const int tid = threadIdx.x;
  const int wave = tid >> 6, lane = tid & 63, g = lane >> 4, c = lane & 15;
  const uint4* src = (const uint4*)(qp + (size_t)bh * 524288 + (size_t)tt * 8192);
#pragma unroll
  for (int u = 0; u < 4; ++u) {
    int li = u * 256 + tid;
    uint4 raw = src[li];
    int t4l = li >> 6;
    int m0 = (li * 2) & 127;
    int trow = t4l * 4;
    union { uint4 u4; unsigned short s[8]; } U; U.u4 = raw;
#pragma unroll
    for (int j = 0; j < 4; ++j) {
      qlds[trow + j][m0] = U.s[j];
      qlds[trow + j][m0 + 1] = U.s[4 + j];
    }
  }
  __syncthreads();
  f32x4 acc[5];
#pragma unroll
  for (int j = 0; j < 5; ++j) acc[j] = (f32x4){0.f, 0.f, 0.f, 0.f};
  const _Float16* kvbase = kvnt + (size_t)bh * 80 * 128;
#pragma unroll
  for (int ks = 0; ks < 4; ++ks) {
    half8 a = *(const half8*)&qlds[wave * 16 + c][ks * 32 + g * 8];
#pragma unroll
    for (int nf = 0; nf < 5; ++nf) {
      half8 bb = *(const half8*)(kvbase + (size_t)(nf * 16 + c) * 128 + ks * 32 + g * 8);
      acc[nf] = __builtin_amdgcn_mfma_f32_16x16x32_f16(a, bb, acc[nf], 0, 0, 0);
    }
  }
  const int tbase = tt * 64 + wave * 16 + g * 4;
#pragma unroll
  for (int j = 0; j < 4; ++j) {
    float nrm = __shfl(acc[4][j], (lane & 48));
    float invn = 1.0f / nrm;
#pragma unroll
    for (int nf = 0; nf < 4; ++nf) {
      out[((size_t)bh * 4096 + tbase + j) * 64 + nf * 16 + c] = acc[nf][j] * invn;
    }
  }
}

extern "C" void kernel_launch(void* const* d_in, const int* in_sizes, int n_in,
                              void* d_out, int out_size, void* d_ws, size_t ws_size,
                              hipStream_t stream) {
  const float* query = (const float*)d_in[0];
  const float* value = (const float*)d_in[1];
  const float* key   = (const float*)d_in[2];
  const float* wq    = (const float*)d_in[3];
  const float* wv    = (const float*)d_in[4];
  const float* wk    = (const float*)d_in[5];
  const float* omega = (const float*)d_in[6];
  float* out = (float*)d_out;
  char* ws = (char*)d_ws;

  _Float16* bigq_h = (_Float16*)(ws);
  _Float16* bigq_l = (_Float16*)(ws + 1048576);
  _Float16* bigk_h = (_Float16*)(ws + 2097152);
  _Float16* bigk_l = (_Float16*)(ws + 3145728);
  _Float16* wvt    = (_Float16*)(ws + 4194304);
  _Float16* qp     = (_Float16*)(ws + 4718592);
  unsigned short* kpt = (unsigned short*)(ws + 38273024);
  unsigned short* vt  = (unsigned short*)(ws + 71827456);
  float* kvpart    = (float*)(ws + 88604672);
  _Float16* kvnt   = (_Float16*)(ws + 99090432);
  float* lsc       = (float*)(ws + 99745792);

  k0_prep<<<5120, 256, 0, stream>>>(wq, wv, wk, omega, bigq_h, bigq_l, bigk_h, bigk_l, wvt);
  k_proj_phi<0><<<256, 512, 0, stream>>>(key, bigk_h, bigk_l, nullptr, nullptr, kpt);
  k_vproj<<<256, 512, 0, stream>>>(value, wvt, vt);
  k3_kv<<<dim3(32, 8), 256, 0, stream>>>(kpt, vt, kvpart);
  k3b_reduce<<<32, 256, 0, stream>>>(kvpart, kvnt, lsc);
  k_proj_phi<1><<<256, 512, 0, stream>>>(query, bigq_h, bigq_l, lsc, qp, nullptr);
  k4_out<<<dim3(64, 32), 256, 0, stream>>>(qp, kvnt, out);
}

// Round 2
// 280.403 us; speedup vs baseline: 1.0356x; 1.0356x over previous
//
#include <hip/hip_runtime.h>

typedef _Float16 half8 __attribute__((ext_vector_type(8)));
typedef _Float16 half4_t __attribute__((ext_vector_type(4)));
typedef short short8 __attribute__((ext_vector_type(8)));
typedef unsigned short u16x4 __attribute__((ext_vector_type(4)));
typedef float f32x4 __attribute__((ext_vector_type(4)));

#define NH 8

__device__ __forceinline__ unsigned short f2bf(float x) {
  union { float f; unsigned u; } v; v.f = x;
  unsigned r = v.u + 0x7FFFu + ((v.u >> 16) & 1u);
  return (unsigned short)(r >> 16);
}

// ---------------- K0: weight prep ----------------
// wxq/wxk: [h][64][512] fp16 hi/lo = (W @ omega^T)^T ; wvt: [h][64][512] fp16
__global__ __launch_bounds__(256) void k0_prep(
    const float* __restrict__ wq, const float* __restrict__ wv,
    const float* __restrict__ wk, const float* __restrict__ omega,
    _Float16* __restrict__ wxq_h, _Float16* __restrict__ wxq_l,
    _Float16* __restrict__ wxk_h, _Float16* __restrict__ wxk_l,
    _Float16* __restrict__ wvt) {
  int idx = blockIdx.x * 256 + threadIdx.x;
  const int NW = 2 * NH * 64 * 512;  // 524288
  if (idx < NW) {
    int arr = idx >> 18;
    int r = idx & 262143;
    int h = r >> 15;
    int o = (r >> 9) & 63;
    int f = r & 511;
    const float* w = arr ? wk : wq;
    const float* wrow = w + (h * 512 + f) * 64;
    const float* om = omega + o * 64;
    float s = 0.f;
#pragma unroll 8
    for (int k = 0; k < 64; ++k) s = fmaf(wrow[k], om[k], s);
    _Float16 hi = (_Float16)s;
    _Float16 lo = (_Float16)(s - (float)hi);
    int off = (h * 64 + o) * 512 + f;
    if (arr == 0) { wxq_h[off] = hi; wxq_l[off] = lo; }
    else          { wxk_h[off] = hi; wxk_l[off] = lo; }
  } else {
    int r = idx - NW;
    if (r < NH * 64 * 512) {
      int h = r >> 15;
      int o = (r >> 9) & 63;
      int f = r & 511;
      wvt[(h * 64 + o) * 512 + f] = (_Float16)wv[(h * 512 + f) * 64 + o];
    }
  }
}

// ---------------- proj+phi: xw = x @ Wxw^T (split fp16, 3-pass), then phi ----------------
// grid 512: blockIdx.x = rt*2 + hp.  8 waves = 4 heads x 2 row-halves; wave: 32 rows.
// QSIDE=1: x=query -> qp fp16 blocked [bh][t/4][128][4]
// QSIDE=0: x=key   -> kpt bf16 [bh][128][4096]
template <int QSIDE>
__global__ __launch_bounds__(512, 4) void k_proj_phi(
    const float* __restrict__ x,
    const _Float16* __restrict__ wx_h,
    const _Float16* __restrict__ wx_l,
    const float* __restrict__ lsc,
    _Float16* __restrict__ qp,
    unsigned short* __restrict__ kpt) {
  __shared__ __align__(16) _Float16 Af[2][512][8];  // [hi/lo][k8*64+row][8] = 16KB
  const int tid = threadIdx.x;
  const int w = tid >> 6;
  const int lane = tid & 63;
  const int g = lane >> 4;
  const int c = lane & 15;
  const int head = (blockIdx.x & 1) * 4 + (w >> 1);
  const int half = w & 1;
  const int R0 = (blockIdx.x >> 1) * 64;
  const int b = R0 >> 12;
  const int t0 = R0 & 4095;
  const int bh = b * NH + head;

  const int srow = tid & 63;
  const int k8 = tid >> 6;
  const int wslot = k8 * 64 + srow;

  f32x4 acc[2][4];
#pragma unroll
  for (int i = 0; i < 2; ++i)
#pragma unroll
    for (int j = 0; j < 4; ++j) acc[i][j] = (f32x4){0.f, 0.f, 0.f, 0.f};

  const _Float16* bhb = wx_h + (size_t)head * 64 * 512;
  const _Float16* blb = wx_l + (size_t)head * 64 * 512;

  for (int kc = 0; kc < 8; ++kc) {
    __syncthreads();
    {
      const float* src = x + (size_t)(R0 + srow) * 512 + kc * 64 + k8 * 8;
      float4 v0 = *(const float4*)(src);
      float4 v1 = *(const float4*)(src + 4);
      float vv[8] = {v0.x, v0.y, v0.z, v0.w, v1.x, v1.y, v1.z, v1.w};
      half8 hv, lv;
#pragma unroll
      for (int i = 0; i < 8; ++i) {
        _Float16 h = (_Float16)vv[i];
        hv[i] = h;
        lv[i] = (_Float16)(vv[i] - (float)h);
      }
      *(half8*)&Af[0][wslot][0] = hv;
      *(half8*)&Af[1][wslot][0] = lv;
    }
    __syncthreads();
#pragma unroll
    for (int ks = 0; ks < 2; ++ks) {
      half8 a_h[2], a_l[2];
#pragma unroll
      for (int mf = 0; mf < 2; ++mf) {
        const int slot = (ks * 4 + g) * 64 + (half * 2 + mf) * 16 + c;
        a_h[mf] = *(const half8*)&Af[0][slot][0];
        a_l[mf] = *(const half8*)&Af[1][slot][0];
      }
      const int koff = kc * 64 + ks * 32 + g * 8;
#pragma unroll
      for (int nf = 0; nf < 4; ++nf) {
        half8 b_h = *(const half8*)(bhb + (size_t)(nf * 16 + c) * 512 + koff);
        half8 b_l = *(const half8*)(blb + (size_t)(nf * 16 + c) * 512 + koff);
#pragma unroll
        for (int mf = 0; mf < 2; ++mf) {
          acc[mf][nf] = __builtin_amdgcn_mfma_f32_16x16x32_f16(a_h[mf], b_h, acc[mf][nf], 0, 0, 0);
          acc[mf][nf] = __builtin_amdgcn_mfma_f32_16x16x32_f16(a_l[mf], b_h, acc[mf][nf], 0, 0, 0);
          acc[mf][nf] = __builtin_amdgcn_mfma_f32_16x16x32_f16(a_h[mf], b_l, acc[mf][nf], 0, 0, 0);
        }
      }
    }
  }

  float Lp[4], Lm[4];
  if (QSIDE) {
#pragma unroll
    for (int nf = 0; nf < 4; ++nf) {
      Lp[nf] = lsc[bh * 128 + nf * 16 + c];
      Lm[nf] = lsc[bh * 128 + 64 + nf * 16 + c];
    }
  }

#pragma unroll
  for (int mf = 0; mf < 2; ++mf) {
    float ss_[4];
#pragma unroll
    for (int j = 0; j < 4; ++j) {
      float s = 0.f;
#pragma unroll
      for (int nf = 0; nf < 4; ++nf) { float q = acc[mf][nf][j]; s = fmaf(q, q, s); }
      s += __shfl_xor(s, 1); s += __shfl_xor(s, 2);
      s += __shfl_xor(s, 4); s += __shfl_xor(s, 8);
      ss_[j] = s * 0.0078125f;  // ||xw||^2 / 128 == 0.5*||q||^2
    }
    if (QSIDE) {
      float cm_[4];
#pragma unroll
      for (int j = 0; j < 4; ++j) {
        float m0 = -1e30f;
#pragma unroll
        for (int nf = 0; nf < 4; ++nf) {
          float v = acc[mf][nf][j];
          float ep = v - ss_[j] + Lp[nf];
          float em = -v - ss_[j] + Lm[nf];
          m0 = fmaxf(m0, fmaxf(ep, em));
          m0 = fmaxf(m0, fmaxf(Lp[nf], Lm[nf]) - 20.723265f);  // eps floor
        }
        m0 = fmaxf(m0, __shfl_xor(m0, 1)); m0 = fmaxf(m0, __shfl_xor(m0, 2));
        m0 = fmaxf(m0, __shfl_xor(m0, 4)); m0 = fmaxf(m0, __shfl_xor(m0, 8));
        cm_[j] = m0;
      }
      const int t4 = (t0 >> 2) + half * 8 + mf * 4 + g;
#pragma unroll
      for (int nf = 0; nf < 4; ++nf) {
        const int m = nf * 16 + c;
        half4_t pp, pm;
#pragma unroll
        for (int j = 0; j < 4; ++j) {
          float v = acc[mf][nf][j];
          pp[j] = (_Float16)(__expf(v - ss_[j] + Lp[nf] - cm_[j]) +
                             1e-9f * __expf(Lp[nf] - cm_[j]));
          pm[j] = (_Float16)(__expf(-v - ss_[j] + Lm[nf] - cm_[j]) +
                             1e-9f * __expf(Lm[nf] - cm_[j]));
        }
        _Float16* outp = qp + ((((size_t)bh * 1024 + t4) * 128 + m) << 2);
        *(half4_t*)outp = pp;
        *(half4_t*)(outp + 256) = pm;  // m+64
      }
    } else {
      const int s_g = t0 + half * 32 + mf * 16 + g * 4;
#pragma unroll
      for (int nf = 0; nf < 4; ++nf) {
        const int m = nf * 16 + c;
        u16x4 kp_p, kp_m;
#pragma unroll
        for (int j = 0; j < 4; ++j) {
          float v = acc[mf][nf][j];
          kp_p[j] = f2bf(__expf(v - ss_[j]) + 1e-9f);
          kp_m[j] = f2bf(__expf(-v - ss_[j]) + 1e-9f);
        }
        unsigned short* outp = kpt + ((size_t)bh * 128 + m) * 4096 + s_g;
        *(u16x4*)outp = kp_p;
        *(u16x4*)(outp + (size_t)64 * 4096) = kp_m;
      }
    }
  }
}

// ---------------- V projection -> VT bf16 [bh][64][4096] ----------------
__global__ __launch_bounds__(512, 4) void k_vproj(
    const float* __restrict__ x, const _Float16* __restrict__ wvt,
    unsigned short* __restrict__ vt) {
  __shared__ __align__(16) _Float16 Af[512][8];  // 8KB
  const int tid = threadIdx.x;
  const int w = tid >> 6;
  const int lane = tid & 63;
  const int g = lane >> 4, c = lane & 15;
  const int head = (blockIdx.x & 1) * 4 + (w >> 1);
  const int half = w & 1;
  const int R0 = (blockIdx.x >> 1) * 64;
  const int b = R0 >> 12;
  const int t0 = R0 & 4095;
  const int bh = b * NH + head;
  const int srow = tid & 63;
  const int k8 = tid >> 6;
  const int wslot = k8 * 64 + srow;

  f32x4 acc[2][4];
#pragma unroll
  for (int i = 0; i < 2; ++i)
#pragma unroll
    for (int j = 0; j < 4; ++j) acc[i][j] = (f32x4){0.f, 0.f, 0.f, 0.f};
  const _Float16* wb = wvt + (size_t)head * 64 * 512;
  for (int kc = 0; kc < 8; ++kc) {
    __syncthreads();
    {
      const float* src = x + (size_t)(R0 + srow) * 512 + kc * 64 + k8 * 8;
      float4 v0 = *(const float4*)(src);
      float4 v1 = *(const float4*)(src + 4);
      float vv[8] = {v0.x, v0.y, v0.z, v0.w, v1.x, v1.y, v1.z, v1.w};
      half8 hv;
#pragma unroll
      for (int i = 0; i < 8; ++i) hv[i] = (_Float16)vv[i];
      *(half8*)&Af[wslot][0] = hv;
    }
    __syncthreads();
#pragma unroll
    for (int ks = 0; ks < 2; ++ks) {
      half8 a_h[2];
#pragma unroll
      for (int mf = 0; mf < 2; ++mf) {
        const int slot = (ks * 4 + g) * 64 + (half * 2 + mf) * 16 + c;
        a_h[mf] = *(const half8*)&Af[slot][0];
      }
      const int koff = kc * 64 + ks * 32 + g * 8;
#pragma unroll
      for (int nf = 0; nf < 4; ++nf) {
        half8 b_h = *(const half8*)(wb + (size_t)(nf * 16 + c) * 512 + koff);
#pragma unroll
        for (int mf = 0; mf < 2; ++mf)
          acc[mf][nf] = __builtin_amdgcn_mfma_f32_16x16x32_f16(a_h[mf], b_h, acc[mf][nf], 0, 0, 0);
      }
    }
  }
#pragma unroll
  for (int mf = 0; mf < 2; ++mf) {
    const int s_g = t0 + half * 32 + mf * 16 + g * 4;
#pragma unroll
    for (int nf = 0; nf < 4; ++nf) {
      u16x4 vv;
#pragma unroll
      for (int j = 0; j < 4; ++j) vv[j] = f2bf(acc[mf][nf][j]);
      *(u16x4*)(vt + ((size_t)bh * 64 + nf * 16 + c) * 4096 + s_g) = vv;
    }
  }
}

// ---------------- K3: kv partials [kc][bh][128][80] fp32 ----------------
// 512 thr = 8 waves, wave = 16 m-rows; grid (32 bh, 8 kc)
__global__ __launch_bounds__(512) void k3_kv(
    const unsigned short* __restrict__ kpt, const unsigned short* __restrict__ vt,
    float* __restrict__ kvpart) {
  const int bh = blockIdx.x;
  const int kc = blockIdx.y;
  const int w = threadIdx.x >> 6;
  const int lane = threadIdx.x & 63;
  const int g = lane >> 4, c = lane & 15;
  f32x4 acc[5];
#pragma unroll
  for (int j = 0; j < 5; ++j) acc[j] = (f32x4){0.f, 0.f, 0.f, 0.f};
  short8 bones;
#pragma unroll
  for (int i = 0; i < 8; ++i) bones[i] = (c == 0) ? (short)0x3F80 : (short)0;
  const unsigned short* kbase = kpt + (size_t)bh * 128 * 4096 + (size_t)(w * 16 + c) * 4096;
  const unsigned short* vbase = vt + (size_t)bh * 64 * 4096;
#pragma unroll 4
  for (int ks = 0; ks < 16; ++ks) {
    const int soff = kc * 512 + ks * 32 + g * 8;
    short8 a0 = *(const short8*)(kbase + soff);
#pragma unroll
    for (int nf = 0; nf < 4; ++nf) {
      short8 bb = *(const short8*)(vbase + (size_t)(nf * 16 + c) * 4096 + soff);
      acc[nf] = __builtin_amdgcn_mfma_f32_16x16x32_bf16(a0, bb, acc[nf], 0, 0, 0);
    }
    acc[4] = __builtin_amdgcn_mfma_f32_16x16x32_bf16(a0, bones, acc[4], 0, 0, 0);
  }
  float* pbase = kvpart + ((size_t)kc * 32 + bh) * 128 * 80;
#pragma unroll
  for (int nf = 0; nf < 5; ++nf)
#pragma unroll
    for (int j = 0; j < 4; ++j) {
      int m = w * 16 + g * 4 + j;
      pbase[m * 80 + nf * 16 + c] = acc[nf][j];
    }
}

// ---------------- K3b: reduce + normalize -> kvnT fp16 [bh][80][128], lsc ----------------
// grid (32, 4): each block handles a 20-wide d-slice
__global__ __launch_bounds__(256) void k3b_reduce(
    const float* __restrict__ kvpart, _Float16* __restrict__ kvnt,
    float* __restrict__ lsc) {
  const int bh = blockIdx.x;
  const int by = blockIdx.y;
  const int tid = threadIdx.x;
  __shared__ float inv[128];
  const float* base = kvpart + (size_t)bh * 128 * 80;
  const size_t stride = (size_t)32 * 128 * 80;
  if (tid < 128) {
    float s = 0.f;
#pragma unroll
    for (int kc = 0; kc < 8; ++kc) s += base[kc * stride + tid * 80 + 64];
    inv[tid] = 1.0f / s;
    if (by == 0) lsc[bh * 128 + tid] = __logf(s);
  }
  __syncthreads();
#pragma unroll
  for (int it = 0; it < 10; ++it) {
    int idx = it * 256 + tid;
    int d = by * 20 + (idx >> 7);
    int m = idx & 127;
    float s = 0.f;
#pragma unroll
    for (int kc = 0; kc < 8; ++kc) s += base[kc * stride + m * 80 + d];
    float val;
    if (d < 64) val = s * inv[m];
    else if (d == 64) val = 1.0f;
    else val = 0.f;
    kvnt[((size_t)bh * 80 + d) * 128 + m] = (_Float16)val;
  }
}

// ---------------- K4: out = (qp2 @ kvn)/(qp2 @ 1) ----------------
__global__ __launch_bounds__(256) void k4_out(
    const _Float16* __restrict__ qp, const _Float16* __restrict__ kvnt,
    float* __restrict__ out) {
  __shared__ unsigned short qlds[64][136];
  const int bh = blockIdx.y;
  const int tt = blockIdx.x;
  const int tid = threadIdx.x;
  const int wave = tid >> 6, lane = tid & 63, g = lane >> 4, c = lane & 15;
  const uint4* src = (const uint4*)(qp + (size_t)bh * 524288 + (size_t)tt * 8192);
#pragma unroll
  for (int u = 0; u < 4; ++u) {
    int li = u * 256 + tid;
    uint4 raw = src[li];
    int t4l = li >> 6;
    int m0 = (li * 2) & 127;
    int trow = t4l * 4;
    union { uint4 u4; unsigned short s[8]; } U; U.u4 = raw;
#pragma unroll
    for (int j = 0; j < 4; ++j) {
      qlds[trow + j][m0] = U.s[j];
      qlds[trow + j][m0 + 1] = U.s[4 + j];
    }
  }
  __syncthreads();
  f32x4 acc[5];
#pragma unroll
  for (int j = 0; j < 5; ++j) acc[j] = (f32x4){0.f, 0.f, 0.f, 0.f};
  const _Float16* kvbase = kvnt + (size_t)bh * 80 * 128;
#pragma unroll
  for (int ks = 0; ks < 4; ++ks) {
    half8 a = *(const half8*)&qlds[wave * 16 + c][ks * 32 + g * 8];
#pragma unroll
    for (int nf = 0; nf < 5; ++nf) {
      half8 bb = *(const half8*)(kvbase + (size_t)(nf * 16 + c) * 128 + ks * 32 + g * 8);
      acc[nf] = __builtin_amdgcn_mfma_f32_16x16x32_f16(a, bb, acc[nf], 0, 0, 0);
    }
  }
  const int tbase = tt * 64 + wave * 16 + g * 4;
#pragma unroll
  for (int j = 0; j < 4; ++j) {
    float nrm = __shfl(acc[4][j], (lane & 48));
    float invn = 1.0f / nrm;
#pragma unroll
    for (int nf = 0; nf < 4; ++nf) {
      out[((size_t)bh * 4096 + tbase + j) * 64 + nf * 16 + c] = acc[nf][j] * invn;
    }
  }
}

extern "C" void kernel_launch(void* const* d_in, const int* in_sizes, int n_in,
                              void* d_out, int out_size, void* d_ws, size_t ws_size,
                              hipStream_t stream) {
  const float* query = (const float*)d_in[0];
  const float* value = (const float*)d_in[1];
  const float* key   = (const float*)d_in[2];
  const float* wq    = (const float*)d_in[3];
  const float* wv    = (const float*)d_in[4];
  const float* wk    = (const float*)d_in[5];
  const float* omega = (const float*)d_in[6];
  float* out = (float*)d_out;
  char* ws = (char*)d_ws;

  _Float16* wxq_h = (_Float16*)(ws);
  _Float16* wxq_l = (_Float16*)(ws + 524288);
  _Float16* wxk_h = (_Float16*)(ws + 1048576);
  _Float16* wxk_l = (_Float16*)(ws + 1572864);
  _Float16* wvt   = (_Float16*)(ws + 2097152);
  _Float16* qp    = (_Float16*)(ws + 2621440);
  unsigned short* kpt = (unsigned short*)(ws + 36175872);
  unsigned short* vt  = (unsigned short*)(ws + 69730304);
  float* kvpart   = (float*)(ws + 86507520);
  _Float16* kvnt  = (_Float16*)(ws + 96993280);
  float* lsc      = (float*)(ws + 97648640);

  k0_prep<<<3072, 256, 0, stream>>>(wq, wv, wk, omega, wxq_h, wxq_l, wxk_h, wxk_l, wvt);
  k_proj_phi<0><<<512, 512, 0, stream>>>(key, wxk_h, wxk_l, nullptr, nullptr, kpt);
  k_vproj<<<512, 512, 0, stream>>>(value, wvt, vt);
  k3_kv<<<dim3(32, 8), 512, 0, stream>>>(kpt, vt, kvpart);
  k3b_reduce<<<dim3(32, 4), 256, 0, stream>>>(kvpart, kvnt, lsc);
  k_proj_phi<1><<<512, 512, 0, stream>>>(query, wxq_h, wxq_l, lsc, qp, nullptr);
  k4_out<<<dim3(64, 32), 256, 0, stream>>>(qp, kvnt, out);
}

// Round 3
// 186.930 us; speedup vs baseline: 1.5534x; 1.5000x over previous
//
#include <hip/hip_runtime.h>

typedef _Float16 half8 __attribute__((ext_vector_type(8)));
typedef _Float16 half4_t __attribute__((ext_vector_type(4)));
typedef short short8 __attribute__((ext_vector_type(8)));
typedef unsigned short u16x4 __attribute__((ext_vector_type(4)));
typedef float f32x4 __attribute__((ext_vector_type(4)));

#define NH 8

__device__ __forceinline__ unsigned short f2bf(float x) {
  union { float f; unsigned u; } v; v.f = x;
  unsigned r = v.u + 0x7FFFu + ((v.u >> 16) & 1u);
  return (unsigned short)(r >> 16);
}

// ---------------- K0a: q/k weight prep -> fragment-major [h][kc][k8][o][8] fp16 hi/lo ----
// grid 128 = arr(2) x h(8) x ftile(8); 256 thr = 4 waves (o-groups) x 64 f-lanes
__global__ __launch_bounds__(256) void k0_qk(
    const float* __restrict__ wq, const float* __restrict__ wk,
    const float* __restrict__ omega,
    _Float16* __restrict__ wxq_h, _Float16* __restrict__ wxq_l,
    _Float16* __restrict__ wxk_h, _Float16* __restrict__ wxk_l) {
  const int bid = blockIdx.x;
  const int arr = bid >> 6;
  const int h = (bid >> 3) & 7;
  const int ft = bid & 7;
  const int f = threadIdx.x & 63;
  const int w = threadIdx.x >> 6;
  const float* wsrc = (arr ? wk : wq) + ((size_t)h * 512 + ft * 64 + f) * 64;
  float wreg[64];
#pragma unroll
  for (int i = 0; i < 16; ++i) {
    float4 v = *(const float4*)(wsrc + i * 4);
    wreg[i * 4] = v.x; wreg[i * 4 + 1] = v.y; wreg[i * 4 + 2] = v.z; wreg[i * 4 + 3] = v.w;
  }
  _Float16* oh = arr ? wxk_h : wxq_h;
  _Float16* ol = arr ? wxk_l : wxq_l;
  const int k8 = f >> 3, e = f & 7;
#pragma unroll 1
  for (int oo = 0; oo < 16; ++oo) {
    const int o = w * 16 + oo;
    const float* om = omega + o * 64;  // wave-uniform -> scalar loads
    float s = 0.f;
#pragma unroll
    for (int k = 0; k < 64; ++k) s = fmaf(wreg[k], om[k], s);
    _Float16 hi = (_Float16)s;
    _Float16 lo = (_Float16)(s - (float)hi);
    size_t off = ((((size_t)h * 8 + ft) * 8 + k8) * 64 + o) * 8 + e;
    oh[off] = hi; ol[off] = lo;
  }
}

// ---------------- K0b: v weight transpose -> fragment-major [h][kc][k8][o][8] fp16 ------
__global__ __launch_bounds__(256) void k0_v(
    const float* __restrict__ wv, _Float16* __restrict__ wvt) {
  int idx = blockIdx.x * 256 + threadIdx.x;  // 262144 total
  int h = idx >> 15, o = (idx >> 9) & 63, f = idx & 511;
  float val = wv[((size_t)h * 512 + f) * 64 + o];
  size_t off = ((((size_t)h * 8 + (f >> 6)) * 8 + ((f >> 3) & 7)) * 64 + o) * 8 + (f & 7);
  wvt[off] = (_Float16)val;
}

// ---------------- proj+phi: xw = x @ Wx^T (split fp16 3-pass) + phi --------------------
// block 512 thr = 8 waves = 2 heads x 4 row-quarters; 128 rows; grid = 128 rowtiles x 4 headpairs
template <int QSIDE>
__global__ __launch_bounds__(512, 4) void k_proj_phi(
    const float* __restrict__ x,
    const _Float16* __restrict__ wx_h,
    const _Float16* __restrict__ wx_l,
    const float* __restrict__ lsc,
    _Float16* __restrict__ qp,
    unsigned short* __restrict__ kpt) {
  __shared__ __align__(16) _Float16 A[2][128][72];   // hi/lo, padded: 36864 B
  __shared__ __align__(16) _Float16 W[4][4096];      // [head*2+part][k8][o][e]: 32768 B
  const int tid = threadIdx.x;
  const int w = tid >> 6;
  const int lane = tid & 63;
  const int g = lane >> 4;
  const int c = lane & 15;
  const int head = w >> 2;   // 0..1
  const int q4 = w & 3;      // row quarter
  const int hp = blockIdx.x & 3;
  const int rt = blockIdx.x >> 2;
  const int R0 = rt * 128;
  const int b = R0 >> 12;
  const int t0 = R0 & 4095;
  const int head0 = hp * 2;
  const int bh = b * NH + head0 + head;

  // staging maps
  const int xr = lane >> 4;          // 0..3
  const int xc = (lane & 15) * 4;    // fp32 col
  const float* xbase = x + (size_t)(R0 + w * 16 + xr) * 512 + xc;
  const _Float16* whb = wx_h + (size_t)head0 * 8 * 4096;
  const _Float16* wlb = wx_l + (size_t)head0 * 8 * 4096;

  float4 xv[4];
  half8 wv_[4];
  // prologue: issue kc=0 loads
#pragma unroll
  for (int i = 0; i < 4; ++i) xv[i] = *(const float4*)(xbase + i * 4 * 512);
#pragma unroll
  for (int hh = 0; hh < 2; ++hh) {
    wv_[hh * 2 + 0] = *(const half8*)(whb + (size_t)hh * 8 * 4096 + tid * 8);
    wv_[hh * 2 + 1] = *(const half8*)(wlb + (size_t)hh * 8 * 4096 + tid * 8);
  }

  f32x4 acc[2][4];
#pragma unroll
  for (int i = 0; i < 2; ++i)
#pragma unroll
    for (int j = 0; j < 4; ++j) acc[i][j] = (f32x4){0.f, 0.f, 0.f, 0.f};

#pragma unroll 1
  for (int kc = 0; kc < 8; ++kc) {
    asm volatile("s_waitcnt lgkmcnt(0)" ::: "memory");
    __builtin_amdgcn_s_barrier();            // all waves done reading prev tile
    __builtin_amdgcn_sched_barrier(0);
    // convert + write A (compiler inserts vmcnt wait for xv)
#pragma unroll
    for (int i = 0; i < 4; ++i) {
      float vv[4] = {xv[i].x, xv[i].y, xv[i].z, xv[i].w};
      half4_t hv, lv;
#pragma unroll
      for (int j2 = 0; j2 < 4; ++j2) {
        _Float16 hc = (_Float16)vv[j2];
        hv[j2] = hc; lv[j2] = (_Float16)(vv[j2] - (float)hc);
      }
      const int row = w * 16 + i * 4 + xr;
      *(half4_t*)&A[0][row][xc] = hv;
      *(half4_t*)&A[1][row][xc] = lv;
    }
#pragma unroll
    for (int ch = 0; ch < 4; ++ch) *(half8*)&W[ch][tid * 8] = wv_[ch];
    // prefetch kc+1 (stays in flight across barrier)
    if (kc < 7) {
#pragma unroll
      for (int i = 0; i < 4; ++i)
        xv[i] = *(const float4*)(xbase + (kc + 1) * 64 + i * 4 * 512);
#pragma unroll
      for (int hh = 0; hh < 2; ++hh) {
        wv_[hh * 2 + 0] = *(const half8*)(whb + ((size_t)hh * 8 + kc + 1) * 4096 + tid * 8);
        wv_[hh * 2 + 1] = *(const half8*)(wlb + ((size_t)hh * 8 + kc + 1) * 4096 + tid * 8);
      }
    }
    asm volatile("s_waitcnt lgkmcnt(0)" ::: "memory");
    __builtin_amdgcn_s_barrier();            // tile ready
    __builtin_amdgcn_sched_barrier(0);
    // compute
#pragma unroll
    for (int ks = 0; ks < 2; ++ks) {
      half8 a_h[2], a_l[2];
#pragma unroll
      for (int mf = 0; mf < 2; ++mf) {
        const int row = q4 * 32 + mf * 16 + c;
        a_h[mf] = *(const half8*)&A[0][row][ks * 32 + g * 8];
        a_l[mf] = *(const half8*)&A[1][row][ks * 32 + g * 8];
      }
#pragma unroll
      for (int nf = 0; nf < 4; ++nf) {
        const int widx = (((ks * 4 + g) * 64) + nf * 16 + c) * 8;
        half8 b_h = *(const half8*)&W[head * 2 + 0][widx];
        half8 b_l = *(const half8*)&W[head * 2 + 1][widx];
#pragma unroll
        for (int mf = 0; mf < 2; ++mf) {
          acc[mf][nf] = __builtin_amdgcn_mfma_f32_16x16x32_f16(a_h[mf], b_h, acc[mf][nf], 0, 0, 0);
          acc[mf][nf] = __builtin_amdgcn_mfma_f32_16x16x32_f16(a_l[mf], b_h, acc[mf][nf], 0, 0, 0);
          acc[mf][nf] = __builtin_amdgcn_mfma_f32_16x16x32_f16(a_h[mf], b_l, acc[mf][nf], 0, 0, 0);
        }
      }
    }
  }

  float Lp[4], Lm[4];
  if (QSIDE) {
#pragma unroll
    for (int nf = 0; nf < 4; ++nf) {
      Lp[nf] = lsc[bh * 128 + nf * 16 + c];
      Lm[nf] = lsc[bh * 128 + 64 + nf * 16 + c];
    }
  }

#pragma unroll
  for (int mf = 0; mf < 2; ++mf) {
    float ss_[4];
#pragma unroll
    for (int j = 0; j < 4; ++j) {
      float s = 0.f;
#pragma unroll
      for (int nf = 0; nf < 4; ++nf) { float q = acc[mf][nf][j]; s = fmaf(q, q, s); }
      s += __shfl_xor(s, 1); s += __shfl_xor(s, 2);
      s += __shfl_xor(s, 4); s += __shfl_xor(s, 8);
      ss_[j] = s * 0.0078125f;  // ||xw||^2/128 == 0.5*||q||^2 (omega orthogonal*sqrt64)
    }
    if (QSIDE) {
      float cm_[4];
#pragma unroll
      for (int j = 0; j < 4; ++j) {
        float m0 = -1e30f;
#pragma unroll
        for (int nf = 0; nf < 4; ++nf) {
          float v = acc[mf][nf][j];
          float ep = v - ss_[j] + Lp[nf];
          float em = -v - ss_[j] + Lm[nf];
          m0 = fmaxf(m0, fmaxf(ep, em));
          m0 = fmaxf(m0, fmaxf(Lp[nf], Lm[nf]) - 20.723265f);  // eps floor
        }
        m0 = fmaxf(m0, __shfl_xor(m0, 1)); m0 = fmaxf(m0, __shfl_xor(m0, 2));
        m0 = fmaxf(m0, __shfl_xor(m0, 4)); m0 = fmaxf(m0, __shfl_xor(m0, 8));
        cm_[j] = m0;
      }
      const int t4 = (t0 >> 2) + q4 * 8 + mf * 4 + g;
#pragma unroll
      for (int nf = 0; nf < 4; ++nf) {
        const int m = nf * 16 + c;
        half4_t pp, pm;
#pragma unroll
        for (int j = 0; j < 4; ++j) {
          float v = acc[mf][nf][j];
          pp[j] = (_Float16)(__expf(v - ss_[j] + Lp[nf] - cm_[j]) +
                             1e-9f * __expf(Lp[nf] - cm_[j]));
          pm[j] = (_Float16)(__expf(-v - ss_[j] + Lm[nf] - cm_[j]) +
                             1e-9f * __expf(Lm[nf] - cm_[j]));
        }
        _Float16* outp = qp + ((((size_t)bh * 1024 + t4) * 128 + m) << 2);
        *(half4_t*)outp = pp;
        *(half4_t*)(outp + 256) = pm;  // m+64
      }
    } else {
      const int s_g = t0 + q4 * 32 + mf * 16 + g * 4;
#pragma unroll
      for (int nf = 0; nf < 4; ++nf) {
        const int m = nf * 16 + c;
        u16x4 kp_p, kp_m;
#pragma unroll
        for (int j = 0; j < 4; ++j) {
          float v = acc[mf][nf][j];
          kp_p[j] = f2bf(__expf(v - ss_[j]) + 1e-9f);
          kp_m[j] = f2bf(__expf(-v - ss_[j]) + 1e-9f);
        }
        unsigned short* outp = kpt + ((size_t)bh * 128 + m) * 4096 + s_g;
        *(u16x4*)outp = kp_p;
        *(u16x4*)(outp + (size_t)64 * 4096) = kp_m;
      }
    }
  }
}

// ---------------- V projection -> VT bf16 [bh][64][4096] ----------------
__global__ __launch_bounds__(512, 4) void k_vproj(
    const float* __restrict__ x, const _Float16* __restrict__ wvt,
    unsigned short* __restrict__ vt) {
  __shared__ __align__(16) _Float16 A[128][72];  // 18432 B
  __shared__ __align__(16) _Float16 W[2][4096];  // 16384 B
  const int tid = threadIdx.x;
  const int w = tid >> 6;
  const int lane = tid & 63;
  const int g = lane >> 4, c = lane & 15;
  const int head = w >> 2;
  const int q4 = w & 3;
  const int hp = blockIdx.x & 3;
  const int rt = blockIdx.x >> 2;
  const int R0 = rt * 128;
  const int b = R0 >> 12;
  const int t0 = R0 & 4095;
  const int head0 = hp * 2;
  const int bh = b * NH + head0 + head;
  const int xr = lane >> 4;
  const int xc = (lane & 15) * 4;
  const float* xbase = x + (size_t)(R0 + w * 16 + xr) * 512 + xc;
  const _Float16* whb = wvt + (size_t)head0 * 8 * 4096;

  float4 xv[4];
  half8 wv_[2];
#pragma unroll
  for (int i = 0; i < 4; ++i) xv[i] = *(const float4*)(xbase + i * 4 * 512);
#pragma unroll
  for (int hh = 0; hh < 2; ++hh)
    wv_[hh] = *(const half8*)(whb + (size_t)hh * 8 * 4096 + tid * 8);

  f32x4 acc[2][4];
#pragma unroll
  for (int i = 0; i < 2; ++i)
#pragma unroll
    for (int j = 0; j < 4; ++j) acc[i][j] = (f32x4){0.f, 0.f, 0.f, 0.f};

#pragma unroll 1
  for (int kc = 0; kc < 8; ++kc) {
    asm volatile("s_waitcnt lgkmcnt(0)" ::: "memory");
    __builtin_amdgcn_s_barrier();
    __builtin_amdgcn_sched_barrier(0);
#pragma unroll
    for (int i = 0; i < 4; ++i) {
      float vv[4] = {xv[i].x, xv[i].y, xv[i].z, xv[i].w};
      half4_t hv;
#pragma unroll
      for (int j2 = 0; j2 < 4; ++j2) hv[j2] = (_Float16)vv[j2];
      const int row = w * 16 + i * 4 + xr;
      *(half4_t*)&A[row][xc] = hv;
    }
#pragma unroll
    for (int ch = 0; ch < 2; ++ch) *(half8*)&W[ch][tid * 8] = wv_[ch];
    if (kc < 7) {
#pragma unroll
      for (int i = 0; i < 4; ++i)
        xv[i] = *(const float4*)(xbase + (kc + 1) * 64 + i * 4 * 512);
#pragma unroll
      for (int hh = 0; hh < 2; ++hh)
        wv_[hh] = *(const half8*)(whb + ((size_t)hh * 8 + kc + 1) * 4096 + tid * 8);
    }
    asm volatile("s_waitcnt lgkmcnt(0)" ::: "memory");
    __builtin_amdgcn_s_barrier();
    __builtin_amdgcn_sched_barrier(0);
#pragma unroll
    for (int ks = 0; ks < 2; ++ks) {
      half8 a_h[2];
#pragma unroll
      for (int mf = 0; mf < 2; ++mf)
        a_h[mf] = *(const half8*)&A[q4 * 32 + mf * 16 + c][ks * 32 + g * 8];
#pragma unroll
      for (int nf = 0; nf < 4; ++nf) {
        const int widx = (((ks * 4 + g) * 64) + nf * 16 + c) * 8;
        half8 b_h = *(const half8*)&W[head][widx];
#pragma unroll
        for (int mf = 0; mf < 2; ++mf)
          acc[mf][nf] = __builtin_amdgcn_mfma_f32_16x16x32_f16(a_h[mf], b_h, acc[mf][nf], 0, 0, 0);
      }
    }
  }
#pragma unroll
  for (int mf = 0; mf < 2; ++mf) {
    const int s_g = t0 + q4 * 32 + mf * 16 + g * 4;
#pragma unroll
    for (int nf = 0; nf < 4; ++nf) {
      u16x4 vvv;
#pragma unroll
      for (int j = 0; j < 4; ++j) vvv[j] = f2bf(acc[mf][nf][j]);
      *(u16x4*)(vt + ((size_t)bh * 64 + nf * 16 + c) * 4096 + s_g) = vvv;
    }
  }
}

// ---------------- K3: kv partials [kc][bh][128][80] fp32 ----------------
__global__ __launch_bounds__(512) void k3_kv(
    const unsigned short* __restrict__ kpt, const unsigned short* __restrict__ vt,
    float* __restrict__ kvpart) {
  const int bh = blockIdx.x;
  const int kc = blockIdx.y;
  const int w = threadIdx.x >> 6;
  const int lane = threadIdx.x & 63;
  const int g = lane >> 4, c = lane & 15;
  f32x4 acc[5];
#pragma unroll
  for (int j = 0; j < 5; ++j) acc[j] = (f32x4){0.f, 0.f, 0.f, 0.f};
  short8 bones;
#pragma unroll
  for (int i = 0; i < 8; ++i) bones[i] = (c == 0) ? (short)0x3F80 : (short)0;
  const unsigned short* kbase = kpt + (size_t)bh * 128 * 4096 + (size_t)(w * 16 + c) * 4096;
  const unsigned short* vbase = vt + (size_t)bh * 64 * 4096;
#pragma unroll 4
  for (int ks = 0; ks < 16; ++ks) {
    const int soff = kc * 512 + ks * 32 + g * 8;
    short8 a0 = *(const short8*)(kbase + soff);
#pragma unroll
    for (int nf = 0; nf < 4; ++nf) {
      short8 bb = *(const short8*)(vbase + (size_t)(nf * 16 + c) * 4096 + soff);
      acc[nf] = __builtin_amdgcn_mfma_f32_16x16x32_bf16(a0, bb, acc[nf], 0, 0, 0);
    }
    acc[4] = __builtin_amdgcn_mfma_f32_16x16x32_bf16(a0, bones, acc[4], 0, 0, 0);
  }
  float* pbase = kvpart + ((size_t)kc * 32 + bh) * 128 * 80;
#pragma unroll
  for (int nf = 0; nf < 5; ++nf)
#pragma unroll
    for (int j = 0; j < 4; ++j) {
      int m = w * 16 + g * 4 + j;
      pbase[m * 80 + nf * 16 + c] = acc[nf][j];
    }
}

// ---------------- K3b: reduce + normalize -> kvnT fp16 [bh][80][128], lsc --------------
__global__ __launch_bounds__(256) void k3b_reduce(
    const float* __restrict__ kvpart, _Float16* __restrict__ kvnt,
    float* __restrict__ lsc) {
  const int bh = blockIdx.x;
  const int by = blockIdx.y;
  const int tid = threadIdx.x;
  __shared__ float inv[128];
  const float* base = kvpart + (size_t)bh * 128 * 80;
  const size_t stride = (size_t)32 * 128 * 80;
  if (tid < 128) {
    float s = 0.f;
#pragma unroll
    for (int kc = 0; kc < 8; ++kc) s += base[kc * stride + tid * 80 + 64];
    inv[tid] = 1.0f / s;
    if (by == 0) lsc[bh * 128 + tid] = __logf(s);
  }
  __syncthreads();
#pragma unroll
  for (int it = 0; it < 10; ++it) {
    int idx = it * 256 + tid;
    int d = by * 20 + (idx >> 7);
    int m = idx & 127;
    float s = 0.f;
#pragma unroll
    for (int kc = 0; kc < 8; ++kc) s += base[kc * stride + m * 80 + d];
    float val;
    if (d < 64) val = s * inv[m];
    else if (d == 64) val = 1.0f;
    else val = 0.f;
    kvnt[((size_t)bh * 80 + d) * 128 + m] = (_Float16)val;
  }
}

// ---------------- K4: out = (qp2 @ kvn)/(qp2 @ 1) ----------------
__global__ __launch_bounds__(256) void k4_out(
    const _Float16* __restrict__ qp, const _Float16* __restrict__ kvnt,
    float* __restrict__ out) {
  __shared__ unsigned short qlds[64][136];
  const int bh = blockIdx.y;
  const int tt = blockIdx.x;
  const int tid = threadIdx.x;
  const int wave = tid >> 6, lane = tid & 63, g = lane >> 4, c = lane & 15;
  const uint4* src = (const uint4*)(qp + (size_t)bh * 524288 + (size_t)tt * 8192);
#pragma unroll
  for (int u = 0; u < 4; ++u) {
    int li = u * 256 + tid;
    uint4 raw = src[li];
    int t4l = li >> 6;
    int m0 = (li * 2) & 127;
    int trow = t4l * 4;
    union { uint4 u4; unsigned short s[8]; } U; U.u4 = raw;
#pragma unroll
    for (int j = 0; j < 4; ++j) {
      qlds[trow + j][m0] = U.s[j];
      qlds[trow + j][m0 + 1] = U.s[4 + j];
    }
  }
  __syncthreads();
  f32x4 acc[5];
#pragma unroll
  for (int j = 0; j < 5; ++j) acc[j] = (f32x4){0.f, 0.f, 0.f, 0.f};
  const _Float16* kvbase = kvnt + (size_t)bh * 80 * 128;
#pragma unroll
  for (int ks = 0; ks < 4; ++ks) {
    half8 a = *(const half8*)&qlds[wave * 16 + c][ks * 32 + g * 8];
#pragma unroll
    for (int nf = 0; nf < 5; ++nf) {
      half8 bb = *(const half8*)(kvbase + (size_t)(nf * 16 + c) * 128 + ks * 32 + g * 8);
      acc[nf] = __builtin_amdgcn_mfma_f32_16x16x32_f16(a, bb, acc[nf], 0, 0, 0);
    }
  }
  const int tbase = tt * 64 + wave * 16 + g * 4;
#pragma unroll
  for (int j = 0; j < 4; ++j) {
    float nrm = __shfl(acc[4][j], (lane & 48));
    float invn = 1.0f / nrm;
#pragma unroll
    for (int nf = 0; nf < 4; ++nf) {
      out[((size_t)bh * 4096 + tbase + j) * 64 + nf * 16 + c] = acc[nf][j] * invn;
    }
  }
}

extern "C" void kernel_launch(void* const* d_in, const int* in_sizes, int n_in,
                              void* d_out, int out_size, void* d_ws, size_t ws_size,
                              hipStream_t stream) {
  const float* query = (const float*)d_in[0];
  const float* value = (const float*)d_in[1];
  const float* key   = (const float*)d_in[2];
  const float* wq    = (const float*)d_in[3];
  const float* wv    = (const float*)d_in[4];
  const float* wk    = (const float*)d_in[5];
  const float* omega = (const float*)d_in[6];
  float* out = (float*)d_out;
  char* ws = (char*)d_ws;

  _Float16* wxq_h = (_Float16*)(ws);
  _Float16* wxq_l = (_Float16*)(ws + 524288);
  _Float16* wxk_h = (_Float16*)(ws + 1048576);
  _Float16* wxk_l = (_Float16*)(ws + 1572864);
  _Float16* wvt   = (_Float16*)(ws + 2097152);
  _Float16* qp    = (_Float16*)(ws + 2621440);
  unsigned short* kpt = (unsigned short*)(ws + 36175872);
  unsigned short* vt  = (unsigned short*)(ws + 69730304);
  float* kvpart   = (float*)(ws + 86507520);
  _Float16* kvnt  = (_Float16*)(ws + 96993280);
  float* lsc      = (float*)(ws + 97648640);

  k0_qk<<<128, 256, 0, stream>>>(wq, wk, omega, wxq_h, wxq_l, wxk_h, wxk_l);
  k0_v<<<1024, 256, 0, stream>>>(wv, wvt);
  k_proj_phi<0><<<512, 512, 0, stream>>>(key, wxk_h, wxk_l, nullptr, nullptr, kpt);
  k_vproj<<<512, 512, 0, stream>>>(value, wvt, vt);
  k3_kv<<<dim3(32, 8), 512, 0, stream>>>(kpt, vt, kvpart);
  k3b_reduce<<<dim3(32, 4), 256, 0, stream>>>(kvpart, kvnt, lsc);
  k_proj_phi<1><<<512, 512, 0, stream>>>(query, wxq_h, wxq_l, lsc, qp, nullptr);
  k4_out<<<dim3(64, 32), 256, 0, stream>>>(qp, kvnt, out);
}

// Round 4
// 140.225 us; speedup vs baseline: 2.0708x; 1.3331x over previous
//
#include <hip/hip_runtime.h>

typedef _Float16 half8 __attribute__((ext_vector_type(8)));
typedef _Float16 half4_t __attribute__((ext_vector_type(4)));
typedef short short8 __attribute__((ext_vector_type(8)));
typedef unsigned short u16x4 __attribute__((ext_vector_type(4)));
typedef float f32x4 __attribute__((ext_vector_type(4)));

#define NH 8

__device__ __forceinline__ unsigned short f2bf(float x) {
  union { float f; unsigned u; } v; v.f = x;
  unsigned r = v.u + 0x7FFFu + ((v.u >> 16) & 1u);
  return (unsigned short)(r >> 16);
}

// ---------------- K0a: q/k weights -> fragment-major [h][kc][k8][o][8] fp16 (hi only) ----
__global__ __launch_bounds__(256) void k0_qk(
    const float* __restrict__ wq, const float* __restrict__ wk,
    const float* __restrict__ omega,
    _Float16* __restrict__ wxq, _Float16* __restrict__ wxk) {
  const int bid = blockIdx.x;           // 128 = arr(2) x h(8) x ftile(8)
  const int arr = bid >> 6;
  const int h = (bid >> 3) & 7;
  const int ft = bid & 7;
  const int f = threadIdx.x & 63;
  const int w = threadIdx.x >> 6;
  const float* wsrc = (arr ? wk : wq) + ((size_t)h * 512 + ft * 64 + f) * 64;
  float wreg[64];
#pragma unroll
  for (int i = 0; i < 16; ++i) {
    float4 v = *(const float4*)(wsrc + i * 4);
    wreg[i * 4] = v.x; wreg[i * 4 + 1] = v.y; wreg[i * 4 + 2] = v.z; wreg[i * 4 + 3] = v.w;
  }
  _Float16* outp = arr ? wxk : wxq;
  const int k8 = f >> 3, e = f & 7;
#pragma unroll 1
  for (int oo = 0; oo < 16; ++oo) {
    const int o = w * 16 + oo;
    const float* om = omega + o * 64;   // wave-uniform -> scalar loads
    float s = 0.f;
#pragma unroll
    for (int k = 0; k < 64; ++k) s = fmaf(wreg[k], om[k], s);
    outp[((((size_t)h * 8 + ft) * 8 + k8) * 64 + o) * 8 + e] = (_Float16)s;
  }
}

// ---------------- K0b: v weights -> fragment-major [h][kc][k8][o][8] fp16 ----------------
__global__ __launch_bounds__(256) void k0_v(
    const float* __restrict__ wv, _Float16* __restrict__ wvt) {
  int idx = blockIdx.x * 256 + threadIdx.x;  // 262144
  int h = idx >> 15, o = (idx >> 9) & 63, f = idx & 511;
  float val = wv[((size_t)h * 512 + f) * 64 + o];
  wvt[((((size_t)h * 8 + (f >> 6)) * 8 + ((f >> 3) & 7)) * 64 + o) * 8 + (f & 7)] = (_Float16)val;
}

// ---------------- fused_kv: proj(key)+phi, proj(value), kv-GEMM -> kvpart ---------------
// grid 512 = h(8 top) x b(4) x sc(16); block 512 = 8 waves x 16 rows
__global__ __launch_bounds__(512, 4) void fused_kv(
    const float* __restrict__ key, const float* __restrict__ value,
    const _Float16* __restrict__ wxk, const _Float16* __restrict__ wvt,
    float* __restrict__ kvpart) {
  __shared__ __align__(16) _Float16 A[128][72];        // 18432 B
  __shared__ __align__(16) _Float16 W[4096];           // 8192 B
  __shared__ __align__(16) unsigned short kpT[128][136]; // 34816 B
  __shared__ __align__(16) unsigned short vT[64][136];   // 17408 B
  const int bid = blockIdx.x;
  const int h = bid >> 6;
  const int b = (bid >> 4) & 3;
  const int sc = bid & 15;
  const int s0 = sc * 256;
  const int bh = b * NH + h;
  const int tid = threadIdx.x;
  const int w = tid >> 6;
  const int lane = tid & 63;
  const int g = lane >> 4, c = lane & 15;
  const int xr = lane >> 4;
  const int xc = (lane & 15) * 4;

  short8 bones;
#pragma unroll
  for (int i = 0; i < 8; ++i) bones[i] = (c == 0) ? (short)0x3F80 : (short)0;

  f32x4 acc_kv[5];
#pragma unroll
  for (int j = 0; j < 5; ++j) acc_kv[j] = (f32x4){0.f, 0.f, 0.f, 0.f};

  // prologue prefetch: p=0 (key, st=0), kc=0
  const float* xb0 = key + (size_t)(b * 4096 + s0 + w * 16 + xr) * 512 + xc;
  const _Float16* wb0 = wxk + (size_t)h * 32768;
  float4 xv[4];
  half8 wr;
#pragma unroll
  for (int i = 0; i < 4; ++i) xv[i] = *(const float4*)(xb0 + i * 2048);
  wr = *(const half8*)(wb0 + tid * 8);

#pragma unroll 1
  for (int p = 0; p < 4; ++p) {
    const float* xb = ((p & 1) ? value : key) +
                      (size_t)(b * 4096 + s0 + (p >> 1) * 128 + w * 16 + xr) * 512 + xc;
    const _Float16* wb = ((p & 1) ? wvt : wxk) + (size_t)h * 32768;

    f32x4 accp[4];
#pragma unroll
    for (int j = 0; j < 4; ++j) accp[j] = (f32x4){0.f, 0.f, 0.f, 0.f};

#pragma unroll 1
    for (int kc = 0; kc < 8; ++kc) {
      asm volatile("s_waitcnt lgkmcnt(0)" ::: "memory");
      __builtin_amdgcn_s_barrier();
      __builtin_amdgcn_sched_barrier(0);
#pragma unroll
      for (int i = 0; i < 4; ++i) {
        float vv[4] = {xv[i].x, xv[i].y, xv[i].z, xv[i].w};
        half4_t hv;
#pragma unroll
        for (int j2 = 0; j2 < 4; ++j2) hv[j2] = (_Float16)vv[j2];
        *(half4_t*)&A[w * 16 + i * 4 + xr][xc] = hv;
      }
      *(half8*)&W[tid * 8] = wr;
      if (kc < 7) {
#pragma unroll
        for (int i = 0; i < 4; ++i)
          xv[i] = *(const float4*)(xb + (kc + 1) * 64 + i * 2048);
        wr = *(const half8*)(wb + (kc + 1) * 4096 + tid * 8);
      } else if (p < 3) {
        const int pn = p + 1;
        const float* xb2 = ((pn & 1) ? value : key) +
                           (size_t)(b * 4096 + s0 + (pn >> 1) * 128 + w * 16 + xr) * 512 + xc;
        const _Float16* wb2 = ((pn & 1) ? wvt : wxk) + (size_t)h * 32768;
#pragma unroll
        for (int i = 0; i < 4; ++i) xv[i] = *(const float4*)(xb2 + i * 2048);
        wr = *(const half8*)(wb2 + tid * 8);
      }
      asm volatile("s_waitcnt lgkmcnt(0)" ::: "memory");
      __builtin_amdgcn_s_barrier();
      __builtin_amdgcn_sched_barrier(0);
#pragma unroll
      for (int ks = 0; ks < 2; ++ks) {
        half8 a = *(const half8*)&A[w * 16 + c][ks * 32 + g * 8];
#pragma unroll
        for (int nf = 0; nf < 4; ++nf) {
          half8 bf = *(const half8*)&W[((ks * 4 + g) * 64 + nf * 16 + c) * 8];
          accp[nf] = __builtin_amdgcn_mfma_f32_16x16x32_f16(a, bf, accp[nf], 0, 0, 0);
        }
      }
    }

    const int sl0 = w * 16 + g * 4;
    if ((p & 1) == 0) {  // key phase: phi -> kpT (bf16)
      float ss_[4];
#pragma unroll
      for (int j = 0; j < 4; ++j) {
        float s = 0.f;
#pragma unroll
        for (int nf = 0; nf < 4; ++nf) { float q = accp[nf][j]; s = fmaf(q, q, s); }
        s += __shfl_xor(s, 1); s += __shfl_xor(s, 2);
        s += __shfl_xor(s, 4); s += __shfl_xor(s, 8);
        ss_[j] = s * 0.0078125f;  // ||xw||^2/128 == 0.5||k||^2
      }
#pragma unroll
      for (int nf = 0; nf < 4; ++nf) {
        const int m = nf * 16 + c;
        u16x4 kp_p, kp_m;
#pragma unroll
        for (int j = 0; j < 4; ++j) {
          float v = accp[nf][j];
          kp_p[j] = f2bf(__expf(v - ss_[j]) + 1e-9f);
          kp_m[j] = f2bf(__expf(-v - ss_[j]) + 1e-9f);
        }
        *(u16x4*)&kpT[m][sl0] = kp_p;
        *(u16x4*)&kpT[64 + m][sl0] = kp_m;
      }
    } else {  // value phase: plain bf16 -> vT, then kv-GEMM
#pragma unroll
      for (int nf = 0; nf < 4; ++nf) {
        u16x4 vv;
#pragma unroll
        for (int j = 0; j < 4; ++j) vv[j] = f2bf(accp[nf][j]);
        *(u16x4*)&vT[nf * 16 + c][sl0] = vv;
      }
      asm volatile("s_waitcnt lgkmcnt(0)" ::: "memory");
      __builtin_amdgcn_s_barrier();
      __builtin_amdgcn_sched_barrier(0);
#pragma unroll
      for (int ks = 0; ks < 4; ++ks) {
        short8 a = *(const short8*)&kpT[w * 16 + c][ks * 32 + g * 8];
#pragma unroll
        for (int nf = 0; nf < 4; ++nf) {
          short8 bb = *(const short8*)&vT[nf * 16 + c][ks * 32 + g * 8];
          acc_kv[nf] = __builtin_amdgcn_mfma_f32_16x16x32_bf16(a, bb, acc_kv[nf], 0, 0, 0);
        }
        acc_kv[4] = __builtin_amdgcn_mfma_f32_16x16x32_bf16(a, bones, acc_kv[4], 0, 0, 0);
      }
      __builtin_amdgcn_s_barrier();
    }
  }

  float* pbase = kvpart + ((size_t)sc * 32 + bh) * 128 * 80;
#pragma unroll
  for (int nf = 0; nf < 5; ++nf)
#pragma unroll
    for (int j = 0; j < 4; ++j) {
      int m = w * 16 + g * 4 + j;
      pbase[m * 80 + nf * 16 + c] = acc_kv[nf][j];
    }
}

// ---------------- K3b: reduce 16 partials -> kvnT fp16 [bh][80][128-permuted], lsc ------
__global__ __launch_bounds__(256) void k3b_reduce(
    const float* __restrict__ kvpart, _Float16* __restrict__ kvnt,
    float* __restrict__ lsc) {
  const int bh = blockIdx.x;
  const int by = blockIdx.y;
  const int tid = threadIdx.x;
  __shared__ float inv[128];
  const float* base = kvpart + (size_t)bh * 128 * 80;
  const size_t stride = (size_t)32 * 128 * 80;
  if (tid < 128) {
    float s = 0.f;
#pragma unroll
    for (int kk = 0; kk < 16; ++kk) s += base[kk * stride + tid * 80 + 64];
    inv[tid] = 1.0f / s;
    if (by == 0) lsc[bh * 128 + tid] = __logf(s);
  }
  __syncthreads();
#pragma unroll
  for (int it = 0; it < 10; ++it) {
    int idx = it * 256 + tid;
    int d = by * 20 + (idx >> 7);
    int m = idx & 127;
    float s = 0.f;
#pragma unroll
    for (int kk = 0; kk < 16; ++kk) s += base[kk * stride + m * 80 + d];
    float val;
    if (d < 64) val = s * inv[m];
    else if (d == 64) val = 1.0f;
    else val = 0.f;
    int mst = ((m & 63) << 1) | (m >> 6);  // match qp {pp,pm} packing
    kvnt[((size_t)bh * 80 + d) * 128 + mst] = (_Float16)val;
  }
}

// ---------------- fused_qo: proj(query)+phi -> qpT (LDS), out-GEMM -> out ---------------
// grid 1024 = h(8 top) x rt(128); block 512 = 8 waves x 16 rows
__global__ __launch_bounds__(512, 4) void fused_qo(
    const float* __restrict__ query, const _Float16* __restrict__ wxq,
    const _Float16* __restrict__ kvnt, const float* __restrict__ lsc,
    float* __restrict__ out) {
  __shared__ __align__(16) _Float16 A[128][72];     // 18432 B
  __shared__ __align__(16) _Float16 W[4096];        // 8192 B
  __shared__ __align__(16) _Float16 qpT[128][136];  // 34816 B
  const int bid = blockIdx.x;
  const int h = bid >> 7;
  const int rt = bid & 127;
  const int R0 = rt * 128;
  const int b = R0 >> 12;
  const int t0 = R0 & 4095;
  const int bh = b * NH + h;
  const int tid = threadIdx.x;
  const int w = tid >> 6;
  const int lane = tid & 63;
  const int g = lane >> 4, c = lane & 15;
  const int xr = lane >> 4;
  const int xc = (lane & 15) * 4;

  const float* xb = query + (size_t)(b * 4096 + t0 + w * 16 + xr) * 512 + xc;
  const _Float16* wb = wxq + (size_t)h * 32768;

  float4 xv[4];
  half8 wr;
#pragma unroll
  for (int i = 0; i < 4; ++i) xv[i] = *(const float4*)(xb + i * 2048);
  wr = *(const half8*)(wb + tid * 8);

  f32x4 accp[4];
#pragma unroll
  for (int j = 0; j < 4; ++j) accp[j] = (f32x4){0.f, 0.f, 0.f, 0.f};

#pragma unroll 1
  for (int kc = 0; kc < 8; ++kc) {
    asm volatile("s_waitcnt lgkmcnt(0)" ::: "memory");
    __builtin_amdgcn_s_barrier();
    __builtin_amdgcn_sched_barrier(0);
#pragma unroll
    for (int i = 0; i < 4; ++i) {
      float vv[4] = {xv[i].x, xv[i].y, xv[i].z, xv[i].w};
      half4_t hv;
#pragma unroll
      for (int j2 = 0; j2 < 4; ++j2) hv[j2] = (_Float16)vv[j2];
      *(half4_t*)&A[w * 16 + i * 4 + xr][xc] = hv;
    }
    *(half8*)&W[tid * 8] = wr;
    if (kc < 7) {
#pragma unroll
      for (int i = 0; i < 4; ++i)
        xv[i] = *(const float4*)(xb + (kc + 1) * 64 + i * 2048);
      wr = *(const half8*)(wb + (kc + 1) * 4096 + tid * 8);
    }
    asm volatile("s_waitcnt lgkmcnt(0)" ::: "memory");
    __builtin_amdgcn_s_barrier();
    __builtin_amdgcn_sched_barrier(0);
#pragma unroll
    for (int ks = 0; ks < 2; ++ks) {
      half8 a = *(const half8*)&A[w * 16 + c][ks * 32 + g * 8];
#pragma unroll
      for (int nf = 0; nf < 4; ++nf) {
        half8 bf = *(const half8*)&W[((ks * 4 + g) * 64 + nf * 16 + c) * 8];
        accp[nf] = __builtin_amdgcn_mfma_f32_16x16x32_f16(a, bf, accp[nf], 0, 0, 0);
      }
    }
  }

  // phi epilogue -> qpT (fp16, {pp,pm} interleaved along feature)
  float Lp[4], Lm[4];
#pragma unroll
  for (int nf = 0; nf < 4; ++nf) {
    Lp[nf] = lsc[bh * 128 + nf * 16 + c];
    Lm[nf] = lsc[bh * 128 + 64 + nf * 16 + c];
  }
  float ss_[4], cm_[4];
#pragma unroll
  for (int j = 0; j < 4; ++j) {
    float s = 0.f;
#pragma unroll
    for (int nf = 0; nf < 4; ++nf) { float q = accp[nf][j]; s = fmaf(q, q, s); }
    s += __shfl_xor(s, 1); s += __shfl_xor(s, 2);
    s += __shfl_xor(s, 4); s += __shfl_xor(s, 8);
    ss_[j] = s * 0.0078125f;
  }
#pragma unroll
  for (int j = 0; j < 4; ++j) {
    float m0 = -1e30f;
#pragma unroll
    for (int nf = 0; nf < 4; ++nf) {
      float v = accp[nf][j];
      m0 = fmaxf(m0, fmaxf(v - ss_[j] + Lp[nf], -v - ss_[j] + Lm[nf]));
      m0 = fmaxf(m0, fmaxf(Lp[nf], Lm[nf]) - 20.723265f);  // eps floor
    }
    m0 = fmaxf(m0, __shfl_xor(m0, 1)); m0 = fmaxf(m0, __shfl_xor(m0, 2));
    m0 = fmaxf(m0, __shfl_xor(m0, 4)); m0 = fmaxf(m0, __shfl_xor(m0, 8));
    cm_[j] = m0;
  }
#pragma unroll
  for (int nf = 0; nf < 4; ++nf) {
    const int m = nf * 16 + c;
#pragma unroll
    for (int j = 0; j < 4; ++j) {
      float v = accp[nf][j];
      _Float16 pp = (_Float16)(__expf(v - ss_[j] + Lp[nf] - cm_[j]) +
                               1e-9f * __expf(Lp[nf] - cm_[j]));
      _Float16 pm = (_Float16)(__expf(-v - ss_[j] + Lm[nf] - cm_[j]) +
                               1e-9f * __expf(Lm[nf] - cm_[j]));
      union { unsigned u; _Float16 hh[2]; } pk;
      pk.hh[0] = pp; pk.hh[1] = pm;
      *(unsigned*)&qpT[w * 16 + g * 4 + j][2 * m] = pk.u;
    }
  }
  asm volatile("s_waitcnt lgkmcnt(0)" ::: "memory");
  __builtin_amdgcn_s_barrier();
  __builtin_amdgcn_sched_barrier(0);

  // out-GEMM
  f32x4 acco[5];
#pragma unroll
  for (int j = 0; j < 5; ++j) acco[j] = (f32x4){0.f, 0.f, 0.f, 0.f};
  const _Float16* kvb = kvnt + (size_t)bh * 80 * 128;
#pragma unroll
  for (int ks = 0; ks < 4; ++ks) {
    half8 a = *(const half8*)&qpT[w * 16 + c][ks * 32 + g * 8];
#pragma unroll
    for (int nf = 0; nf < 5; ++nf) {
      half8 bb = *(const half8*)(kvb + (size_t)(nf * 16 + c) * 128 + ks * 32 + g * 8);
      acco[nf] = __builtin_amdgcn_mfma_f32_16x16x32_f16(a, bb, acco[nf], 0, 0, 0);
    }
  }
  const int tb = t0 + w * 16 + g * 4;
#pragma unroll
  for (int j = 0; j < 4; ++j) {
    float nrm = __shfl(acco[4][j], (lane & 48));
    float invn = 1.0f / nrm;
#pragma unroll
    for (int nf = 0; nf < 4; ++nf) {
      out[((size_t)bh * 4096 + tb + j) * 64 + nf * 16 + c] = acco[nf][j] * invn;
    }
  }
}

extern "C" void kernel_launch(void* const* d_in, const int* in_sizes, int n_in,
                              void* d_out, int out_size, void* d_ws, size_t ws_size,
                              hipStream_t stream) {
  const float* query = (const float*)d_in[0];
  const float* value = (const float*)d_in[1];
  const float* key   = (const float*)d_in[2];
  const float* wq    = (const float*)d_in[3];
  const float* wv    = (const float*)d_in[4];
  const float* wk    = (const float*)d_in[5];
  const float* omega = (const float*)d_in[6];
  float* out = (float*)d_out;
  char* ws = (char*)d_ws;

  _Float16* wxq  = (_Float16*)(ws);
  _Float16* wxk  = (_Float16*)(ws + 524288);
  _Float16* wvt  = (_Float16*)(ws + 1048576);
  float* kvpart  = (float*)(ws + 1572864);      // 16*32*128*80*4 = 20971520
  _Float16* kvnt = (_Float16*)(ws + 22544384);  // 655360
  float* lsc     = (float*)(ws + 23199744);     // 16384

  k0_qk<<<128, 256, 0, stream>>>(wq, wk, omega, wxq, wxk);
  k0_v<<<1024, 256, 0, stream>>>(wv, wvt);
  fused_kv<<<512, 512, 0, stream>>>(key, value, wxk, wvt, kvpart);
  k3b_reduce<<<dim3(32, 4), 256, 0, stream>>>(kvpart, kvnt, lsc);
  fused_qo<<<1024, 512, 0, stream>>>(query, wxq, kvnt, lsc, out);
}